// Round 15
// baseline (268.107 us; speedup 1.0000x reference)
//
#include <hip/hip_runtime.h>
#include <hip/hip_bf16.h>
#include <stdint.h>

// LimitRegressor = relu(x@W1+b1)@W2+b2 followed by a fixed-point iteration
// whose unique fixed point is y*=out (tanh contraction; global early-exit at
// eps=1e-6 fires at k~13 with residual < 3e-7 << the 6.09e-2 threshold).
// So we emit out directly: two bf16 MFMA GEMMs (w8 2-phase structure:
// 256x256 tile, BK=64, 8 waves 2Mx4N, mfma 16x16x32, counted vmcnt,
// chunk-XOR swizzle (0 conflicts), setprio, XCD-aware mapping).
//
//  - GEMM1 (K=1024): PERSISTENT, 256 wgs (1/CU), R14 XCD remap (4 grps x
//    8 bns per XCD). R15: (a) A prefetch deepened to t+2 via 3-buffer A
//    rotation (LDS 160KB = 3x32K A + 2x32K B; VMW(8)/tile; stage->certify
//    ~3 phases for BOTH operands), (b) non-temporal h-stores so the 134MB
//    write stream stops evicting the staging working set from L2/L3
//    (G1's FETCH=98MB vs 41MB inputs showed 2-4x re-fetch; G2, identical
//    structure minus the write pressure, runs 1.47x faster per tile).
//  - GEMM2 (K=4096, 256 wgs = 1 round): R6 verbatim.

#define DEV __device__ __forceinline__

typedef short bf16x8 __attribute__((ext_vector_type(8)));
typedef float f32x4 __attribute__((ext_vector_type(4)));

typedef __attribute__((address_space(1))) const unsigned char* gptr1_t;
typedef __attribute__((address_space(3))) unsigned char* lptr3_t;

DEV void async_copy16(const void* g, void* l) {
  __builtin_amdgcn_global_load_lds((gptr1_t)g, (lptr3_t)l, 16, 0, 0);
}

DEV unsigned short f2bf(float f) {
  union { float f; unsigned u; } v; v.f = f;
  unsigned u = v.u + 0x7FFFu + ((v.u >> 16) & 1u);  // RNE
  return (unsigned short)(u >> 16);
}

#define BAR()  __builtin_amdgcn_s_barrier()
#define VMW(n) asm volatile("s_waitcnt vmcnt(" #n ")" ::: "memory")

// ---------------- prep kernels (BW-roofline ~23us) ----------------

__global__ void cvt_f32_bf16(const float4* __restrict__ in,
                             ushort4* __restrict__ out, int n4) {
  int i = blockIdx.x * blockDim.x + threadIdx.x;
  if (i >= n4) return;
  float4 v = in[i];
  ushort4 o;
  o.x = f2bf(v.x); o.y = f2bf(v.y); o.z = f2bf(v.z); o.w = f2bf(v.w);
  out[i] = o;
}

// f32 [R][C] row-major  ->  bf16 [C][R] row-major (W -> W^T as bf16)
__global__ void transpose_f32_bf16(const float* __restrict__ in,
                                   unsigned short* __restrict__ out,
                                   int R, int C) {
  __shared__ float tile[32][33];
  int c0 = blockIdx.x * 32, r0 = blockIdx.y * 32;
  int tx = threadIdx.x, ty = threadIdx.y;  // block (32, 8)
#pragma unroll
  for (int i = 0; i < 32; i += 8)
    tile[ty + i][tx] = in[(long)(r0 + ty + i) * C + (c0 + tx)];
  __syncthreads();
#pragma unroll
  for (int i = 0; i < 32; i += 8)
    out[(long)(c0 + ty + i) * R + (r0 + tx)] = f2bf(tile[tx][ty + i]);
}

// ---------------- shared w8 building blocks ----------------
// LDS per operand buf: 4 chunks of 8KB; chunk c = rows [c*64,c*64+64) x
// k[0,64) bf16, 16B-chunk XOR swizzle: LDS[row][c16] = global k-chunk
// (c16 ^ (row&7)). Staged with pre-swizzled global source (both-sides rule).

#define LDA(base, m, ks) \
  (*(const bf16x8*)((base) + abase + (m) * 2048 + (c0 ^ ((ks) << 6))))
#define LDB(base, n, ks) \
  (*(const bf16x8*)((base) + bbase + (n) * 2048 + (c0 ^ ((ks) << 6))))

#define RD_A(dst, base, m0_)                                   \
  _Pragma("unroll") for (int m_ = 0; m_ < 4; ++m_) {           \
    dst[m_][0] = LDA(base, (m0_) + m_, 0);                     \
    dst[m_][1] = LDA(base, (m0_) + m_, 1);                     \
  }
#define RD_B(dst, base, n0_)                                   \
  _Pragma("unroll") for (int n_ = 0; n_ < 2; ++n_) {           \
    dst[n_][0] = LDB(base, (n0_) + n_, 0);                     \
    dst[n_][1] = LDB(base, (n0_) + n_, 1);                     \
  }

#define QUAD(MB, NB, AF, BF)                                                \
  do {                                                                      \
    __builtin_amdgcn_s_setprio(1);                                          \
    _Pragma("unroll") for (int m_ = 0; m_ < 4; ++m_)                        \
    _Pragma("unroll") for (int n_ = 0; n_ < 2; ++n_) {                      \
      acc[(MB) + m_][(NB) + n_] = __builtin_amdgcn_mfma_f32_16x16x32_bf16(  \
          AF[m_][0], BF[n_][0], acc[(MB) + m_][(NB) + n_], 0, 0, 0);        \
      acc[(MB) + m_][(NB) + n_] = __builtin_amdgcn_mfma_f32_16x16x32_bf16(  \
          AF[m_][1], BF[n_][1], acc[(MB) + m_][(NB) + n_], 0, 0, 0);        \
    }                                                                       \
    __builtin_amdgcn_s_setprio(0);                                          \
  } while (0)

#define ST_A_LO(dstw, koff) { async_copy16(gA[0] + (koff), (dstw));          \
                              async_copy16(gA[2] + (koff), (dstw) + 16384); }
#define ST_A_HI(dstw, koff) { async_copy16(gA[1] + (koff), (dstw) + 8192);   \
                              async_copy16(gA[3] + (koff), (dstw) + 24576); }
#define ST_B_LO(dstw, koff) { async_copy16(gB[0] + (koff), (dstw));          \
                              async_copy16(gB[1] + (koff), (dstw) + 8192); }
#define ST_B_HI(dstw, koff) { async_copy16(gB[2] + (koff), (dstw) + 16384);  \
                              async_copy16(gB[3] + (koff), (dstw) + 24576); }

// ====== Kernel A: persistent w8 2-phase, 3-buf A, NT stores (GEMM1) =======
// Grid 256. wg owns (grp, bn) via R14 XCD remap; streams 64 global tiles
// (4 M-panels x 16 K-tiles) through one pipeline. LDS: A bufs at
// 0/32K/64K (tile g -> buf g%3), B bufs at 96K/128K (parity). VMW(8)/tile.

__global__ __launch_bounds__(512, 2)
void gemm_w8p(const unsigned short* __restrict__ A,   // bf16 [16384][K]
              const unsigned short* __restrict__ BT,  // bf16 [Ndim][K]
              const float* __restrict__ bias,         // [Ndim]
              unsigned short* __restrict__ O,         // bf16 [16384][Ndim]
              int K, int Ndim) {                      // 1024, 4096
  extern __shared__ char lds[];

  const int tid = threadIdx.x;
  const int wave = tid >> 6, lane = tid & 63;
  const int wr = wave >> 2, wc = wave & 3;
  const int woff = wave * 1024;

  // R14 remap: XCD x covers 4 grps x 8 bns (inst. L2 set ~6MB).
  const int xcd = blockIdx.x & 7;
  const int jj = blockIdx.x >> 3;          // 0..31
  const int grp = ((xcd >> 1) << 2) | (jj >> 3);
  const int bn = ((xcd & 1) << 3) | (jj & 7);
  const int n0 = bn << 8;
  const int m0base = grp << 10;            // 4 M-panels of 256 rows

  const int srow = tid >> 3;
  const int sk = ((tid & 7) ^ (srow & 7)) << 3;
  const unsigned short* gA[4];
  const unsigned short* gB[4];
#pragma unroll
  for (int c = 0; c < 4; ++c) {
    gA[c] = A + (size_t)(m0base + c * 64 + srow) * K + sk;
    gB[c] = BT + (size_t)(n0 + c * 64 + srow) * K + sk;
  }

  const int lr = lane & 15, lg = lane >> 4;
  const int c0 = ((lg ^ (lr & 7)) << 4);
  const int abase = (wr * 128 + lr) * 128;
  const int bbase = (wc * 64 + lr) * 128;
  const int ccol = n0 + wc * 64;

  f32x4 acc[8][4] = {};
  bf16x8 af[4][2], b01[2][2], b23[2][2];
  float bv[4];
#pragma unroll
  for (int n = 0; n < 4; ++n) bv[n] = bias[ccol + n * 16 + lr];

  // tile g -> A offset (M-panel g>>4, K-tile g&15); B offset (K-tile only)
#define AOFF(g) ((size_t)((g) >> 4) * ((size_t)K << 8) + (size_t)(((g) & 15) << 6))
#define BOFF(g) ((size_t)(((g) & 15) << 6))

#define PEPI(j_)                                                              \
  { const int crow = m0base + (j_) * 256 + wr * 128;                          \
    _Pragma("unroll") for (int m = 0; m < 8; ++m)                             \
    _Pragma("unroll") for (int jq = 0; jq < 4; ++jq) {                        \
      size_t r = (size_t)(crow + m * 16 + lg * 4 + jq) * Ndim;                \
      _Pragma("unroll") for (int n = 0; n < 4; ++n) {                         \
        float v = acc[m][n][jq] + bv[n];                                      \
        __builtin_nontemporal_store(f2bf(fmaxf(v, 0.0f)),                     \
                                    &O[r + ccol + n * 16 + lr]);              \
      } } }

#define ZEROACC()                                                             \
  _Pragma("unroll") for (int m = 0; m < 8; ++m)                               \
  _Pragma("unroll") for (int n = 0; n < 4; ++n)                               \
    acc[m][n] = (f32x4){0.f, 0.f, 0.f, 0.f};

  // prologue: A(0), B(0), A(1), B(1); VMW(8) leaves A(1),B(1) in flight
  {
    char* a0w = lds + woff;
    char* a1w = lds + 32768 + woff;
    char* b0w = lds + 98304 + woff;
    char* b1w = lds + 131072 + woff;
    ST_A_LO(a0w, 0);       ST_A_HI(a0w, 0);
    ST_B_LO(b0w, 0);       ST_B_HI(b0w, 0);
    ST_A_LO(a1w, AOFF(1)); ST_A_HI(a1w, AOFF(1));
    ST_B_LO(b1w, BOFF(1)); ST_B_HI(b1w, BOFF(1));
  }
  VMW(8);
  BAR();

  // steady: tiles 0..61 stage tile g+2 (A -> buf (g+2)%3, B -> parity g%2)
  int ia = 0, ia2 = 2, ib = 0;
  for (int g = 0; g < 62; ++g) {
    const char* aB = lds + ia * 32768;
    const char* bB = lds + 98304 + ib * 32768;
    char* aSw = lds + ia2 * 32768 + woff;
    char* bSw = lds + 98304 + ib * 32768 + woff;
    const size_t ka = AOFF(g + 2), kb = BOFF(g + 2);
    // Ph1
    RD_B(b01, bB, 0); RD_A(af, aB, 0); RD_B(b23, bB, 2);
    ST_A_LO(aSw, ka); ST_A_HI(aSw, ka);
    QUAD(0, 0, af, b01); QUAD(0, 2, af, b23);
    BAR();
    // Ph2
    RD_A(af, aB, 4);
    ST_B_LO(bSw, kb); ST_B_HI(bSw, kb);
    QUAD(4, 2, af, b23); QUAD(4, 0, af, b01);
    VMW(8); BAR();
    // M-panel boundary: flush (stores drain by next tile's VMW)
    if ((g & 15) == 15) { PEPI(g >> 4); ZEROACC(); }
    ia = (ia == 2) ? 0 : ia + 1;
    ia2 = (ia2 == 2) ? 0 : ia2 + 1;
    ib ^= 1;
  }
  // peel g=62 (A buf 2, B parity 0), g=63 (A buf 0, B parity 1)
  {
    const char* aB = lds + 2 * 32768;
    const char* bB = lds + 98304;
    RD_B(b01, bB, 0); RD_A(af, aB, 0); RD_B(b23, bB, 2);
    QUAD(0, 0, af, b01); QUAD(0, 2, af, b23);
    BAR();
    RD_A(af, aB, 4);
    QUAD(4, 2, af, b23); QUAD(4, 0, af, b01);
    VMW(0); BAR();
  }
  {
    const char* aB = lds;
    const char* bB = lds + 131072;
    RD_B(b01, bB, 0); RD_A(af, aB, 0); RD_B(b23, bB, 2);
    QUAD(0, 0, af, b01); QUAD(0, 2, af, b23);
    BAR();
    RD_A(af, aB, 4);
    QUAD(4, 2, af, b23); QUAD(4, 0, af, b01);
  }
  PEPI(3);
#undef PEPI
#undef ZEROACC
#undef AOFF
#undef BOFF
}

// ================= Kernel B: w8 2-phase GEMM (GEMM2) ======================
// Round-6 verbatim.

template <bool RELU_BF16>
__global__ __launch_bounds__(512, 2)
void gemm_w8(const unsigned short* __restrict__ A,   // bf16 [M][K]
             const unsigned short* __restrict__ BT,  // bf16 [N][K]
             const float* __restrict__ bias,         // [N]
             void* __restrict__ Cout,                // bf16 or f32 [M][N]
             int M, int N, int K, int nbn_shift) {
  extern __shared__ char lds[];
  const char* aE = lds;
  const char* aO = lds + 32768;
  const char* bE = lds + 65536;
  const char* bO = lds + 98304;

  const int tid = threadIdx.x;
  const int wave = tid >> 6, lane = tid & 63;
  const int wr = wave >> 2, wc = wave & 3;

  char* aEw = (char*)aE + wave * 1024;
  char* aOw = (char*)aO + wave * 1024;
  char* bEw = (char*)bE + wave * 1024;
  char* bOw = (char*)bO + wave * 1024;

  const int nwg = gridDim.x;
  const int wg = blockIdx.x;
  const int swz = (wg & 7) * (nwg >> 3) + (wg >> 3);
  const int bm = swz >> nbn_shift;
  const int bn = swz & ((1 << nbn_shift) - 1);
  const int m0 = bm << 8, n0 = bn << 8;

  const int srow = tid >> 3;
  const int sk = ((tid & 7) ^ (srow & 7)) << 3;
  const unsigned short* gA[4];
  const unsigned short* gB[4];
#pragma unroll
  for (int c = 0; c < 4; ++c) {
    gA[c] = A + (size_t)(m0 + c * 64 + srow) * K + sk;
    gB[c] = BT + (size_t)(n0 + c * 64 + srow) * K + sk;
  }

  const int lr = lane & 15, lg = lane >> 4;
  const int c0 = ((lg ^ (lr & 7)) << 4);
  const int abase = (wr * 128 + lr) * 128;
  const int bbase = (wc * 64 + lr) * 128;

  f32x4 acc[8][4] = {};
  bf16x8 af[4][2], b01[2][2], b23[2][2];

  ST_B_LO(bEw, 0);  ST_B_HI(bEw, 0);
  ST_A_LO(aEw, 0);  ST_A_HI(aEw, 0);
  ST_B_LO(bOw, 64); ST_B_HI(bOw, 64);
  VMW(4);
  BAR();

  const int NT = K >> 6;

  for (int it = 0; it < (NT - 2) / 2; ++it) {
    const int kE = (2 * it) << 6;
    RD_B(b01, bE, 0); RD_A(af, aE, 0); RD_B(b23, bE, 2);
    ST_A_LO(aOw, kE + 64); ST_A_HI(aOw, kE + 64);
    QUAD(0, 0, af, b01); QUAD(0, 2, af, b23);
    BAR();
    RD_A(af, aE, 4);
    ST_B_LO(bEw, kE + 128); ST_B_HI(bEw, kE + 128);
    QUAD(4, 2, af, b23); QUAD(4, 0, af, b01);
    VMW(4); BAR();
    RD_B(b01, bO, 0); RD_A(af, aO, 0); RD_B(b23, bO, 2);
    ST_A_LO(aEw, kE + 128); ST_A_HI(aEw, kE + 128);
    QUAD(0, 0, af, b01); QUAD(0, 2, af, b23);
    BAR();
    RD_A(af, aO, 4);
    ST_B_LO(bOw, kE + 192); ST_B_HI(bOw, kE + 192);
    QUAD(4, 2, af, b23); QUAD(4, 0, af, b01);
    VMW(4); BAR();
  }
  {
    const int kL = (NT - 1) << 6;
    RD_B(b01, bE, 0); RD_A(af, aE, 0); RD_B(b23, bE, 2);
    ST_A_LO(aOw, kL); ST_A_HI(aOw, kL);
    QUAD(0, 0, af, b01); QUAD(0, 2, af, b23);
    BAR();
    RD_A(af, aE, 4);
    QUAD(4, 2, af, b23); QUAD(4, 0, af, b01);
    VMW(0); BAR();
    RD_B(b01, bO, 0); RD_A(af, aO, 0); RD_B(b23, bO, 2);
    QUAD(0, 0, af, b01); QUAD(0, 2, af, b23);
    BAR();
    RD_A(af, aO, 4);
    QUAD(4, 2, af, b23); QUAD(4, 0, af, b01);
  }

  const int ccol = n0 + wc * 64;
  const int crow = m0 + wr * 128;
  float bv[4];
#pragma unroll
  for (int n = 0; n < 4; ++n) bv[n] = bias[ccol + n * 16 + lr];

  if (RELU_BF16) {
    unsigned short* O = (unsigned short*)Cout;
#pragma unroll
    for (int m = 0; m < 8; ++m)
#pragma unroll
      for (int j = 0; j < 4; ++j) {
        size_t r = (size_t)(crow + m * 16 + lg * 4 + j) * N;
#pragma unroll
        for (int n = 0; n < 4; ++n) {
          float v = acc[m][n][j] + bv[n];
          O[r + ccol + n * 16 + lr] = f2bf(fmaxf(v, 0.0f));
        }
      }
  } else {
    float* O = (float*)Cout;
#pragma unroll
    for (int m = 0; m < 8; ++m)
#pragma unroll
      for (int j = 0; j < 4; ++j) {
        size_t r = (size_t)(crow + m * 16 + lg * 4 + j) * N;
#pragma unroll
        for (int n = 0; n < 4; ++n)
          O[r + ccol + n * 16 + lr] = acc[m][n][j] + bv[n];
      }
  }
}

// ---------------- launch ----------------

extern "C" void kernel_launch(void* const* d_in, const int* in_sizes, int n_in,
                              void* d_out, int out_size, void* d_ws,
                              size_t ws_size, hipStream_t stream) {
  const float* x  = (const float*)d_in[0];   // [16384,1024]
  const float* W1 = (const float*)d_in[1];   // [1024,4096]
  const float* b1 = (const float*)d_in[2];   // [4096]
  const float* W2 = (const float*)d_in[3];   // [4096,1024]
  const float* b2 = (const float*)d_in[4];   // [1024]
  float* out = (float*)d_out;                // [16384,1024] f32

  const int B = 16384, DIN = 1024, DH = 4096, DOUT = 1024;

  size_t need = (size_t)B * DIN * 2 + (size_t)DIN * DH * 2 +
                (size_t)DH * DOUT * 2 + (size_t)B * DH * 2;
  if (ws_size < need) return;

  char* ws = (char*)d_ws;
  unsigned short* xb  = (unsigned short*)ws;  ws += (size_t)B * DIN * 2;
  unsigned short* w1t = (unsigned short*)ws;  ws += (size_t)DIN * DH * 2;  // [DH][DIN]
  unsigned short* w2t = (unsigned short*)ws;  ws += (size_t)DH * DOUT * 2; // [DOUT][DH]
  unsigned short* h   = (unsigned short*)ws;                               // [B][DH]

  hipFuncSetAttribute((const void*)gemm_w8p,
                      hipFuncAttributeMaxDynamicSharedMemorySize, 163840);
  hipFuncSetAttribute((const void*)gemm_w8<false>,
                      hipFuncAttributeMaxDynamicSharedMemorySize, 131072);

  int n4 = B * DIN / 4;
  cvt_f32_bf16<<<n4 / 256, 256, 0, stream>>>((const float4*)x, (ushort4*)xb, n4);
  transpose_f32_bf16<<<dim3(DH / 32, DIN / 32), dim3(32, 8), 0, stream>>>(W1, w1t, DIN, DH);
  transpose_f32_bf16<<<dim3(DOUT / 32, DH / 32), dim3(32, 8), 0, stream>>>(W2, w2t, DH, DOUT);

  // h = relu(x @ W1 + b1) : persistent, 256 wgs, 160KB LDS, deep-A prefetch
  gemm_w8p<<<dim3(256), 512, 163840, stream>>>(xb, w1t, b1, h, DIN, DH);
  // out = h @ W2 + b2     : M=16384, N=1024, K=4096 (NT=64), 256 wgs
  gemm_w8<false><<<dim3((B / 256) * (DOUT / 256)), 512, 131072, stream>>>(
      h, w2t, b2, out, B, DOUT, DH, 2);
}

// Round 16
// 263.305 us; speedup vs baseline: 1.0182x; 1.0182x over previous
//
#include <hip/hip_runtime.h>
#include <hip/hip_bf16.h>
#include <stdint.h>

// LimitRegressor = relu(x@W1+b1)@W2+b2 followed by a fixed-point iteration
// whose unique fixed point is y*=out (tanh contraction; global early-exit at
// eps=1e-6 fires at k~13 with residual < 3e-7 << the 6.09e-2 threshold).
// So we emit out directly: two bf16 MFMA GEMMs (R14 champion, re-banked
// after R15's NT-store experiment regressed: NT hint broke L2 write-
// combining of the stride-32B 2B stores -> +43MB HBM writes = +7us):
//  - GEMM1 (K=1024): PERSISTENT w8 2-phase. 256 wgs (1/CU), each owns
//    (grp,bn) via XCD remap (4 grps x 8 bns per XCD -> ~6MB inst. L2 set);
//    streams 4 M-panels x 16 K-tiles through one continuous pipeline; acc
//    flushed at panel boundaries after the VMW(4);BAR certification point.
//  - GEMM2 (K=4096, 256 wgs = 1 round): w8 2-phase (R6 verbatim).
// 15-round ledger: all structural variants (2/4/8-phase, ILP4, reg-dbuf,
// persistent, deep-prefetch, NT-stores) land 36-41% MfmaUtil; both pipes
// unsaturated -> residual is instruction-level schedule quality not
// reachable from this plain-HIP skeleton. 445 -> 265us total (1.68x).

#define DEV __device__ __forceinline__

typedef short bf16x8 __attribute__((ext_vector_type(8)));
typedef float f32x4 __attribute__((ext_vector_type(4)));

typedef __attribute__((address_space(1))) const unsigned char* gptr1_t;
typedef __attribute__((address_space(3))) unsigned char* lptr3_t;

DEV void async_copy16(const void* g, void* l) {
  __builtin_amdgcn_global_load_lds((gptr1_t)g, (lptr3_t)l, 16, 0, 0);
}

DEV unsigned short f2bf(float f) {
  union { float f; unsigned u; } v; v.f = f;
  unsigned u = v.u + 0x7FFFu + ((v.u >> 16) & 1u);  // RNE
  return (unsigned short)(u >> 16);
}

#define BAR()  __builtin_amdgcn_s_barrier()
#define VMW(n) asm volatile("s_waitcnt vmcnt(" #n ")" ::: "memory")

// ---------------- prep kernels (BW-roofline ~23us) ----------------

__global__ void cvt_f32_bf16(const float4* __restrict__ in,
                             ushort4* __restrict__ out, int n4) {
  int i = blockIdx.x * blockDim.x + threadIdx.x;
  if (i >= n4) return;
  float4 v = in[i];
  ushort4 o;
  o.x = f2bf(v.x); o.y = f2bf(v.y); o.z = f2bf(v.z); o.w = f2bf(v.w);
  out[i] = o;
}

// f32 [R][C] row-major  ->  bf16 [C][R] row-major (W -> W^T as bf16)
__global__ void transpose_f32_bf16(const float* __restrict__ in,
                                   unsigned short* __restrict__ out,
                                   int R, int C) {
  __shared__ float tile[32][33];
  int c0 = blockIdx.x * 32, r0 = blockIdx.y * 32;
  int tx = threadIdx.x, ty = threadIdx.y;  // block (32, 8)
#pragma unroll
  for (int i = 0; i < 32; i += 8)
    tile[ty + i][tx] = in[(long)(r0 + ty + i) * C + (c0 + tx)];
  __syncthreads();
#pragma unroll
  for (int i = 0; i < 32; i += 8)
    out[(long)(c0 + ty + i) * R + (r0 + tx)] = f2bf(tile[tx][ty + i]);
}

// ---------------- shared w8 building blocks ----------------
// LDS per operand per buf: 4 chunks of 8KB; chunk c = rows [c*64,c*64+64) x
// k[0,64) bf16, 16B-chunk XOR swizzle: LDS[row][c16] = global k-chunk
// (c16 ^ (row&7)). Staged with pre-swizzled global source (both-sides rule).

#define LDA(base, m, ks) \
  (*(const bf16x8*)((base) + abase + (m) * 2048 + (c0 ^ ((ks) << 6))))
#define LDB(base, n, ks) \
  (*(const bf16x8*)((base) + bbase + (n) * 2048 + (c0 ^ ((ks) << 6))))

#define RD_A(dst, base, m0_)                                   \
  _Pragma("unroll") for (int m_ = 0; m_ < 4; ++m_) {           \
    dst[m_][0] = LDA(base, (m0_) + m_, 0);                     \
    dst[m_][1] = LDA(base, (m0_) + m_, 1);                     \
  }
#define RD_B(dst, base, n0_)                                   \
  _Pragma("unroll") for (int n_ = 0; n_ < 2; ++n_) {           \
    dst[n_][0] = LDB(base, (n0_) + n_, 0);                     \
    dst[n_][1] = LDB(base, (n0_) + n_, 1);                     \
  }

#define QUAD(MB, NB, AF, BF)                                                \
  do {                                                                      \
    __builtin_amdgcn_s_setprio(1);                                          \
    _Pragma("unroll") for (int m_ = 0; m_ < 4; ++m_)                        \
    _Pragma("unroll") for (int n_ = 0; n_ < 2; ++n_) {                      \
      acc[(MB) + m_][(NB) + n_] = __builtin_amdgcn_mfma_f32_16x16x32_bf16(  \
          AF[m_][0], BF[n_][0], acc[(MB) + m_][(NB) + n_], 0, 0, 0);        \
      acc[(MB) + m_][(NB) + n_] = __builtin_amdgcn_mfma_f32_16x16x32_bf16(  \
          AF[m_][1], BF[n_][1], acc[(MB) + m_][(NB) + n_], 0, 0, 0);        \
    }                                                                       \
    __builtin_amdgcn_s_setprio(0);                                          \
  } while (0)

#define ST_A_LO(dstw, koff) { async_copy16(gA[0] + (koff), (dstw));          \
                              async_copy16(gA[2] + (koff), (dstw) + 16384); }
#define ST_A_HI(dstw, koff) { async_copy16(gA[1] + (koff), (dstw) + 8192);   \
                              async_copy16(gA[3] + (koff), (dstw) + 24576); }
#define ST_B_LO(dstw, koff) { async_copy16(gB[0] + (koff), (dstw));          \
                              async_copy16(gB[1] + (koff), (dstw) + 8192); }
#define ST_B_HI(dstw, koff) { async_copy16(gB[2] + (koff), (dstw) + 16384);  \
                              async_copy16(gB[3] + (koff), (dstw) + 24576); }

// ============ Kernel A: persistent w8 2-phase (GEMM1, K=1024) =============
// Grid 256. wg owns bn and grp; loops 4 M-panels x 16 K-tiles = 64 global
// tiles g through ONE pipeline. Flush at g%16==15.

__global__ __launch_bounds__(512, 2)
void gemm_w8p(const unsigned short* __restrict__ A,   // bf16 [16384][K]
              const unsigned short* __restrict__ BT,  // bf16 [Ndim][K]
              const float* __restrict__ bias,         // [Ndim]
              unsigned short* __restrict__ O,         // bf16 [16384][Ndim]
              int K, int Ndim) {                      // 1024, 4096
  extern __shared__ char lds[];
  const char* aE = lds;
  const char* aO = lds + 32768;
  const char* bE = lds + 65536;
  const char* bO = lds + 98304;

  const int tid = threadIdx.x;
  const int wave = tid >> 6, lane = tid & 63;
  const int wr = wave >> 2, wc = wave & 3;

  char* aEw = (char*)aE + wave * 1024;
  char* aOw = (char*)aO + wave * 1024;
  char* bEw = (char*)bE + wave * 1024;
  char* bOw = (char*)bO + wave * 1024;

  // XCD x covers 4 grps x 8 bns (inst. L2 set ~6MB).
  const int xcd = blockIdx.x & 7;
  const int jj = blockIdx.x >> 3;          // 0..31
  const int grp = ((xcd >> 1) << 2) | (jj >> 3);
  const int bn = ((xcd & 1) << 3) | (jj & 7);
  const int n0 = bn << 8;
  const int m0base = grp << 10;            // 4 M-panels of 256 rows

  const int srow = tid >> 3;
  const int sk = ((tid & 7) ^ (srow & 7)) << 3;
  const unsigned short* gA[4];
  const unsigned short* gB[4];
#pragma unroll
  for (int c = 0; c < 4; ++c) {
    gA[c] = A + (size_t)(m0base + c * 64 + srow) * K + sk;
    gB[c] = BT + (size_t)(n0 + c * 64 + srow) * K + sk;
  }

  const int lr = lane & 15, lg = lane >> 4;
  const int c0 = ((lg ^ (lr & 7)) << 4);
  const int abase = (wr * 128 + lr) * 128;
  const int bbase = (wc * 64 + lr) * 128;
  const int ccol = n0 + wc * 64;

  f32x4 acc[8][4] = {};
  bf16x8 af[4][2], b01[2][2], b23[2][2];
  float bv[4];
#pragma unroll
  for (int n = 0; n < 4; ++n) bv[n] = bias[ccol + n * 16 + lr];

  // global-tile offsets: tile g -> M-panel g>>4 (A rows +256 each), K-tile g&15
#define AOFF(g) ((size_t)((g) >> 4) * ((size_t)K << 8) + (size_t)(((g) & 15) << 6))
#define BOFF(g) ((size_t)(((g) & 15) << 6))

#define PEPI(j_)                                                              \
  { const int crow = m0base + (j_) * 256 + wr * 128;                          \
    _Pragma("unroll") for (int m = 0; m < 8; ++m)                             \
    _Pragma("unroll") for (int jq = 0; jq < 4; ++jq) {                        \
      size_t r = (size_t)(crow + m * 16 + lg * 4 + jq) * Ndim;                \
      _Pragma("unroll") for (int n = 0; n < 4; ++n) {                         \
        float v = acc[m][n][jq] + bv[n];                                      \
        O[r + ccol + n * 16 + lr] = f2bf(fmaxf(v, 0.0f));                     \
      } } }

#define ZEROACC()                                                             \
  _Pragma("unroll") for (int m = 0; m < 8; ++m)                               \
  _Pragma("unroll") for (int n = 0; n < 4; ++n)                               \
    acc[m][n] = (f32x4){0.f, 0.f, 0.f, 0.f};

  // prologue: B(0), A(0), B(1); certify B(0)+A(0), leave B(1) in flight
  ST_B_LO(bEw, 0);        ST_B_HI(bEw, 0);
  ST_A_LO(aEw, 0);        ST_A_HI(aEw, 0);
  ST_B_LO(bOw, BOFF(1));  ST_B_HI(bOw, BOFF(1));
  VMW(4);
  BAR();

  // 64 global tiles; pairs (E=2it, O=2it+1), peel last pair.
  for (int it = 0; it < 31; ++it) {
    const int gE = 2 * it, gO = 2 * it + 1;
    // ---- tile E ----
    RD_B(b01, bE, 0); RD_A(af, aE, 0); RD_B(b23, bE, 2);
    ST_A_LO(aOw, AOFF(gE + 1)); ST_A_HI(aOw, AOFF(gE + 1));
    QUAD(0, 0, af, b01); QUAD(0, 2, af, b23);
    BAR();
    RD_A(af, aE, 4);
    ST_B_LO(bEw, BOFF(gE + 2)); ST_B_HI(bEw, BOFF(gE + 2));
    QUAD(4, 2, af, b23); QUAD(4, 0, af, b01);
    VMW(4); BAR();
    // ---- tile O ----
    RD_B(b01, bO, 0); RD_A(af, aO, 0); RD_B(b23, bO, 2);
    ST_A_LO(aEw, AOFF(gO + 1)); ST_A_HI(aEw, AOFF(gO + 1));
    QUAD(0, 0, af, b01); QUAD(0, 2, af, b23);
    BAR();
    RD_A(af, aO, 4);
    ST_B_LO(bOw, BOFF(gO + 2)); ST_B_HI(bOw, BOFF(gO + 2));
    QUAD(4, 2, af, b23); QUAD(4, 0, af, b01);
    VMW(4); BAR();
    // ---- M-panel boundary (gO = 15, 31, 47): flush acc ----
    if ((it & 7) == 7) {
      PEPI(gO >> 4);
      ZEROACC();
    }
  }
  // ---- peel tiles 62, 63 ----
  RD_B(b01, bE, 0); RD_A(af, aE, 0); RD_B(b23, bE, 2);
  ST_A_LO(aOw, AOFF(63)); ST_A_HI(aOw, AOFF(63));
  QUAD(0, 0, af, b01); QUAD(0, 2, af, b23);
  BAR();
  RD_A(af, aE, 4);
  QUAD(4, 2, af, b23); QUAD(4, 0, af, b01);
  VMW(0); BAR();
  RD_B(b01, bO, 0); RD_A(af, aO, 0); RD_B(b23, bO, 2);
  QUAD(0, 0, af, b01); QUAD(0, 2, af, b23);
  BAR();
  RD_A(af, aO, 4);
  QUAD(4, 2, af, b23); QUAD(4, 0, af, b01);
  PEPI(3);
#undef PEPI
#undef ZEROACC
#undef AOFF
#undef BOFF
}

// ================= Kernel B: w8 2-phase GEMM (GEMM2) ======================
// Round-6 verbatim.

template <bool RELU_BF16>
__global__ __launch_bounds__(512, 2)
void gemm_w8(const unsigned short* __restrict__ A,   // bf16 [M][K]
             const unsigned short* __restrict__ BT,  // bf16 [N][K]
             const float* __restrict__ bias,         // [N]
             void* __restrict__ Cout,                // bf16 or f32 [M][N]
             int M, int N, int K, int nbn_shift) {
  extern __shared__ char lds[];
  const char* aE = lds;
  const char* aO = lds + 32768;
  const char* bE = lds + 65536;
  const char* bO = lds + 98304;

  const int tid = threadIdx.x;
  const int wave = tid >> 6, lane = tid & 63;
  const int wr = wave >> 2, wc = wave & 3;

  char* aEw = (char*)aE + wave * 1024;
  char* aOw = (char*)aO + wave * 1024;
  char* bEw = (char*)bE + wave * 1024;
  char* bOw = (char*)bO + wave * 1024;

  const int nwg = gridDim.x;
  const int wg = blockIdx.x;
  const int swz = (wg & 7) * (nwg >> 3) + (wg >> 3);
  const int bm = swz >> nbn_shift;
  const int bn = swz & ((1 << nbn_shift) - 1);
  const int m0 = bm << 8, n0 = bn << 8;

  const int srow = tid >> 3;
  const int sk = ((tid & 7) ^ (srow & 7)) << 3;
  const unsigned short* gA[4];
  const unsigned short* gB[4];
#pragma unroll
  for (int c = 0; c < 4; ++c) {
    gA[c] = A + (size_t)(m0 + c * 64 + srow) * K + sk;
    gB[c] = BT + (size_t)(n0 + c * 64 + srow) * K + sk;
  }

  const int lr = lane & 15, lg = lane >> 4;
  const int c0 = ((lg ^ (lr & 7)) << 4);
  const int abase = (wr * 128 + lr) * 128;
  const int bbase = (wc * 64 + lr) * 128;

  f32x4 acc[8][4] = {};
  bf16x8 af[4][2], b01[2][2], b23[2][2];

  ST_B_LO(bEw, 0);  ST_B_HI(bEw, 0);
  ST_A_LO(aEw, 0);  ST_A_HI(aEw, 0);
  ST_B_LO(bOw, 64); ST_B_HI(bOw, 64);
  VMW(4);
  BAR();

  const int NT = K >> 6;

  for (int it = 0; it < (NT - 2) / 2; ++it) {
    const int kE = (2 * it) << 6;
    RD_B(b01, bE, 0); RD_A(af, aE, 0); RD_B(b23, bE, 2);
    ST_A_LO(aOw, kE + 64); ST_A_HI(aOw, kE + 64);
    QUAD(0, 0, af, b01); QUAD(0, 2, af, b23);
    BAR();
    RD_A(af, aE, 4);
    ST_B_LO(bEw, kE + 128); ST_B_HI(bEw, kE + 128);
    QUAD(4, 2, af, b23); QUAD(4, 0, af, b01);
    VMW(4); BAR();
    RD_B(b01, bO, 0); RD_A(af, aO, 0); RD_B(b23, bO, 2);
    ST_A_LO(aEw, kE + 128); ST_A_HI(aEw, kE + 128);
    QUAD(0, 0, af, b01); QUAD(0, 2, af, b23);
    BAR();
    RD_A(af, aO, 4);
    ST_B_LO(bOw, kE + 192); ST_B_HI(bOw, kE + 192);
    QUAD(4, 2, af, b23); QUAD(4, 0, af, b01);
    VMW(4); BAR();
  }
  {
    const int kL = (NT - 1) << 6;
    RD_B(b01, bE, 0); RD_A(af, aE, 0); RD_B(b23, bE, 2);
    ST_A_LO(aOw, kL); ST_A_HI(aOw, kL);
    QUAD(0, 0, af, b01); QUAD(0, 2, af, b23);
    BAR();
    RD_A(af, aE, 4);
    QUAD(4, 2, af, b23); QUAD(4, 0, af, b01);
    VMW(0); BAR();
    RD_B(b01, bO, 0); RD_A(af, aO, 0); RD_B(b23, bO, 2);
    QUAD(0, 0, af, b01); QUAD(0, 2, af, b23);
    BAR();
    RD_A(af, aO, 4);
    QUAD(4, 2, af, b23); QUAD(4, 0, af, b01);
  }

  const int ccol = n0 + wc * 64;
  const int crow = m0 + wr * 128;
  float bv[4];
#pragma unroll
  for (int n = 0; n < 4; ++n) bv[n] = bias[ccol + n * 16 + lr];

  if (RELU_BF16) {
    unsigned short* O = (unsigned short*)Cout;
#pragma unroll
    for (int m = 0; m < 8; ++m)
#pragma unroll
      for (int j = 0; j < 4; ++j) {
        size_t r = (size_t)(crow + m * 16 + lg * 4 + j) * N;
#pragma unroll
        for (int n = 0; n < 4; ++n) {
          float v = acc[m][n][j] + bv[n];
          O[r + ccol + n * 16 + lr] = f2bf(fmaxf(v, 0.0f));
        }
      }
  } else {
    float* O = (float*)Cout;
#pragma unroll
    for (int m = 0; m < 8; ++m)
#pragma unroll
      for (int j = 0; j < 4; ++j) {
        size_t r = (size_t)(crow + m * 16 + lg * 4 + j) * N;
#pragma unroll
        for (int n = 0; n < 4; ++n)
          O[r + ccol + n * 16 + lr] = acc[m][n][j] + bv[n];
      }
  }
}

// ---------------- launch ----------------

extern "C" void kernel_launch(void* const* d_in, const int* in_sizes, int n_in,
                              void* d_out, int out_size, void* d_ws,
                              size_t ws_size, hipStream_t stream) {
  const float* x  = (const float*)d_in[0];   // [16384,1024]
  const float* W1 = (const float*)d_in[1];   // [1024,4096]
  const float* b1 = (const float*)d_in[2];   // [4096]
  const float* W2 = (const float*)d_in[3];   // [4096,1024]
  const float* b2 = (const float*)d_in[4];   // [1024]
  float* out = (float*)d_out;                // [16384,1024] f32

  const int B = 16384, DIN = 1024, DH = 4096, DOUT = 1024;

  size_t need = (size_t)B * DIN * 2 + (size_t)DIN * DH * 2 +
                (size_t)DH * DOUT * 2 + (size_t)B * DH * 2;
  if (ws_size < need) return;

  char* ws = (char*)d_ws;
  unsigned short* xb  = (unsigned short*)ws;  ws += (size_t)B * DIN * 2;
  unsigned short* w1t = (unsigned short*)ws;  ws += (size_t)DIN * DH * 2;  // [DH][DIN]
  unsigned short* w2t = (unsigned short*)ws;  ws += (size_t)DH * DOUT * 2; // [DOUT][DH]
  unsigned short* h   = (unsigned short*)ws;                               // [B][DH]

  hipFuncSetAttribute((const void*)gemm_w8p,
                      hipFuncAttributeMaxDynamicSharedMemorySize, 131072);
  hipFuncSetAttribute((const void*)gemm_w8<false>,
                      hipFuncAttributeMaxDynamicSharedMemorySize, 131072);

  int n4 = B * DIN / 4;
  cvt_f32_bf16<<<n4 / 256, 256, 0, stream>>>((const float4*)x, (ushort4*)xb, n4);
  transpose_f32_bf16<<<dim3(DH / 32, DIN / 32), dim3(32, 8), 0, stream>>>(W1, w1t, DIN, DH);
  transpose_f32_bf16<<<dim3(DOUT / 32, DH / 32), dim3(32, 8), 0, stream>>>(W2, w2t, DH, DOUT);

  // h = relu(x @ W1 + b1) : persistent, 256 wgs, 4 M-panels x 16 K-tiles
  gemm_w8p<<<dim3(256), 512, 131072, stream>>>(xb, w1t, b1, h, DIN, DH);
  // out = h @ W2 + b2     : M=16384, N=1024, K=4096 (NT=64), 256 wgs
  gemm_w8<false><<<dim3((B / 256) * (DOUT / 256)), 512, 131072, stream>>>(
      h, w2t, b2, out, B, DOUT, DH, 2);
}